// Round 25
// baseline (293.848 us; speedup 1.0000x reference)
//
#include <hip/hip_runtime.h>
#include <hip/hip_bf16.h>
#include <math.h>
#include <stdint.h>

#define N_POS 4096
#define C_DIM 256
#define CQK_D 32

typedef __attribute__((ext_vector_type(8))) short bf16x8;
typedef __attribute__((ext_vector_type(4))) float f32x4;
typedef __attribute__((ext_vector_type(4))) uint32_t u32x4;

// bf16 conversions via HIP intrinsics: compiler folds pairs to v_cvt_pk_bf16_f32.
__device__ inline uint16_t f2bf(float f){
  union { __hip_bfloat16 h; uint16_t u; } c;
  c.h = __float2bfloat16(f);
  return c.u;
}
__device__ inline uint32_t pk2bf(float a, float b){
  union { __hip_bfloat162 h; uint32_t u; } c;
  c.h = __float22bfloat162_rn(float2{a, b});
  return c.u;
}
__device__ inline float bf2f_lo(uint32_t d){ return __uint_as_float(d << 16); }
__device__ inline float bf2f_hi(uint32_t d){ return __uint_as_float(d & 0xFFFF0000u); }

// ---------------- prep: x transpose -> xT_bf [B][N][256], W concat -> W_bf[320][256], bias_f[320]
__global__ __launch_bounds__(256) void prep(
    const float* __restrict__ x,
    const float* __restrict__ Wq, const float* __restrict__ bq,
    const float* __restrict__ Wk, const float* __restrict__ bk,
    const float* __restrict__ Wv, const float* __restrict__ bv,
    ushort* __restrict__ xT_bf, ushort* __restrict__ W_bf, float* __restrict__ bias_f)
{
    const int tid = threadIdx.x;
    if (blockIdx.x == 64) {
        const int sub = blockIdx.z * 4 + blockIdx.y;   // 0..15
        const int e0 = sub * 5120;
        #pragma unroll
        for (int it = 0; it < 5; ++it) {
            const int e = e0 + (it*256 + tid)*4;
            const int o = e >> 8, c = e & 255;
            float4 w;
            if (o < 32)       w = *reinterpret_cast<const float4*>(&Wq[o*C_DIM + c]);
            else if (o < 64)  w = *reinterpret_cast<const float4*>(&Wk[(o-32)*C_DIM + c]);
            else              w = *reinterpret_cast<const float4*>(&Wv[(o-64)*C_DIM + c]);
            uint2 u; u.x = pk2bf(w.x, w.y); u.y = pk2bf(w.z, w.w);
            *reinterpret_cast<uint2*>(W_bf + e) = u;
        }
        if (sub == 0) {
            for (int i = tid; i < 320; i += 256)
                bias_f[i] = (i < 32) ? bq[i] : (i < 64) ? bk[i-32] : bv[i-64];
        }
        return;
    }
    __shared__ float t[64][65];
    const int jj4 = (tid & 15) * 4;
    const int rg  = tid >> 4;
    const int n0 = blockIdx.x * 64;
    const int c0 = blockIdx.y * 64;
    const int b  = blockIdx.z;
    #pragma unroll
    for (int ii = 0; ii < 4; ++ii) {
        const int cl = ii*16 + rg;
        const float4 xv = *reinterpret_cast<const float4*>(
            &x[((size_t)(b*C_DIM) + c0 + cl)*N_POS + n0 + jj4]);
        float* tr = &t[cl][jj4];
        tr[0] = xv.x; tr[1] = xv.y; tr[2] = xv.z; tr[3] = xv.w;
    }
    __syncthreads();
    #pragma unroll
    for (int ii = 0; ii < 8; ++ii) {
        const int flat = ii*256 + tid;
        const int nl = flat >> 5;
        const int cp = flat & 31;
        const uint32_t d = pk2bf(t[2*cp][nl], t[2*cp+1][nl]);
        *reinterpret_cast<uint32_t*>(xT_bf + ((size_t)(b*N_POS) + n0 + nl)*C_DIM + c0 + 2*cp) = d;
    }
}

// ---------------- qkv projection as bf16 MFMA GEMM (o-split x4) ----------------
__global__ __launch_bounds__(256, 4) void qkv_gemm(
    const ushort* __restrict__ xT_bf, const ushort* __restrict__ W_bf,
    const float* __restrict__ bias_f,
    ushort* __restrict__ q_bf, ushort* __restrict__ k_bf, ushort* __restrict__ v_bf)
{
    __shared__ ushort xs[64*C_DIM];      // 32 KB, XOR-swizzled rows of 512B
    const int tid  = threadIdx.x;
    const int wv   = tid >> 6;
    const int lane = tid & 63;
    const int g    = lane >> 4;
    const int q    = lane & 15;
    const int y    = blockIdx.y;
    const int b    = blockIdx.z;
    const int n0   = blockIdx.x * 64;

    {
        const char* xTb = (const char*)(xT_bf + ((size_t)(b*N_POS) + n0)*C_DIM);
        const int n_l    = (tid*16) >> 9;
        const int inner  = (tid & 31) << 4;
        #pragma unroll
        for (int s = 0; s < 8; ++s) {
            const int n = s*8 + n_l;
            const int src_inner = inner ^ ((n & 7) << 4);
            __builtin_amdgcn_global_load_lds(
                (const __attribute__((address_space(1))) uint32_t*)(xTb + (size_t)n*512 + src_inner),
                (__attribute__((address_space(3))) uint32_t*)((char*)xs + s*4096 + wv*1024),
                16, 0, 0);
        }
    }
    __syncthreads();

    f32x4 zero4 = {0.f,0.f,0.f,0.f};
    f32x4 acc[5];
    #pragma unroll
    for (int i = 0; i < 5; ++i) acc[i] = zero4;

    const char* xrow = (const char*)xs + (wv*16 + q)*512;
    const int sw = (q & 7) << 4;

    #pragma unroll
    for (int kk = 0; kk < 8; ++kk) {
        const bf16x8 xf = *reinterpret_cast<const bf16x8*>(xrow + ((kk*64 + g*16) ^ sw));
        const ushort* wrow = W_bf + (y*80 + q)*C_DIM + kk*32 + g*8;
        #pragma unroll
        for (int i = 0; i < 5; ++i) {
            const bf16x8 wf = *reinterpret_cast<const bf16x8*>(wrow + i*16*C_DIM);
            acc[i] = __builtin_amdgcn_mfma_f32_16x16x32_bf16(wf, xf, acc[i], 0, 0, 0);
        }
    }

    const int n = n0 + wv*16 + q;
    #pragma unroll
    for (int i = 0; i < 5; ++i) {
        const int got = y*5 + i;
        const int ob  = got*16 + 4*g;
        const float4 bi = *reinterpret_cast<const float4*>(bias_f + ob);
        if (got < 4) {
            const uint32_t u0 = pk2bf(acc[i][0] + bi.x, acc[i][1] + bi.y);
            const uint32_t u1 = pk2bf(acc[i][2] + bi.z, acc[i][3] + bi.w);
            ushort* dst = (got < 2 ? q_bf : k_bf) + ((size_t)(b*N_POS) + n)*CQK_D + (ob & 31);
            uint2 u; u.x = u0; u.y = u1;
            *reinterpret_cast<uint2*>(dst) = u;
        } else {
            const int c = ob - 64;
            ushort* vB = v_bf + (size_t)(b*C_DIM)*N_POS + n;
            vB[(size_t)(c+0)*N_POS] = f2bf(acc[i][0] + bi.x);
            vB[(size_t)(c+1)*N_POS] = f2bf(acc[i][1] + bi.y);
            vB[(size_t)(c+2)*N_POS] = f2bf(acc[i][2] + bi.z);
            vB[(size_t)(c+3)*N_POS] = f2bf(acc[i][3] + bi.w);
        }
    }
}

// ---------------- Flash attention: split-KV x ns, channel-split PV ----------------
// r12 chunk semantics; vt halved by TIME-SHARING the wave-private slice:
// lo channels (0..31) staged pre-barrier, hi channels (32..63) staged post-barrier
// after the lo vf reads (in-order per-wave LDS makes this safe). LDS 33 KB ->
// 4 blocks/CU; with ns=4 the grid is exactly 4/CU (16 waves/CU vs 12).
__global__ __launch_bounds__(256, 4) void flash_mfma(
    const ushort* __restrict__ q_bf, const ushort* __restrict__ k_bf,
    const ushort* __restrict__ v_bf, ushort* __restrict__ o_part,
    float* __restrict__ lsum, int nsplit)
{
    __shared__ ushort vt[C_DIM*32];      // 16 KB: per-wave 4KB slice [32 rows][64k] swizzled
    __shared__ ushort pt[2][4*16*64];    // 2 x 8 KB
    __shared__ float  l_s[64];

    const int tid  = threadIdx.x;
    const int wv   = tid >> 6;
    const int lane = tid & 63;
    const int g    = lane >> 4;
    const int q    = lane & 15;
    const int half = blockIdx.y;         // 0..nsplit-1
    const int b    = blockIdx.z;
    const int n0   = blockIdx.x * 64;
    const int qrow = n0 + wv*16 + q;
    int mt0, mt1;
    if (nsplit == 4) { mt0 = half*16; mt1 = mt0 + 16; }
    else { mt0 = (half == 0) ? 0 : 22 + (half-1)*21; mt1 = mt0 + ((half == 0) ? 22 : 21); }

    const ushort* qb = q_bf + (size_t)b*N_POS*CQK_D;
    const ushort* kb = k_bf + (size_t)b*N_POS*CQK_D;
    const ushort* vb = v_bf + (size_t)b*C_DIM*N_POS;

    const bf16x8 qfrag = *reinterpret_cast<const bf16x8*>(qb + (size_t)qrow*CQK_D + g*8);

    f32x4 zero4 = {0.f, 0.f, 0.f, 0.f};
    f32x4 acc[4][4];                     // [ct][qt]
    #pragma unroll
    for (int i = 0; i < 4; ++i)
        #pragma unroll
        for (int j = 0; j < 4; ++j) acc[i][j] = zero4;
    float l = 0.f;

    const int swq = (q & 7) << 4;
    const int st_hi = lane >> 3, st_lo = lane & 7;
    const ushort* vsrc0 = vb + (size_t)(wv*64 + st_hi)*N_POS + st_lo*8;
    // wave slice = vt + wv*4096 (32 rows x 128B); row&7 == st_hi preserved
    char* vdst0 = (char*)vt + wv*4096 + st_hi*128 + (((st_lo ^ st_hi) & 7) << 4);

    auto loadK = [&](int mtx, bf16x8* kf) {
        const int mm = mtx * 64;
        #pragma unroll
        for (int t = 0; t < 4; ++t)
            kf[t] = *reinterpret_cast<const bf16x8*>(kb + (size_t)(mm + t*16 + q)*CQK_D + g*8);
    };

    auto chunk = [&](int mtx, bf16x8* kfc, bf16x8* kfn, int pfmt) {
        const int m0 = mtx * 64;
        const int buf = mtx & 1;
        char* ptw = (char*)pt[buf] + wv*2048;

        // ---- phase A ----
        u32x4 vreg[8];                   // all 64 channels loaded early (T14)
        #pragma unroll
        for (int s = 0; s < 8; ++s)
            vreg[s] = *reinterpret_cast<const u32x4*>(vsrc0 + (size_t)s*8*N_POS + m0);

        f32x4 sv[4];
        #pragma unroll
        for (int t = 0; t < 4; ++t)
            sv[t] = __builtin_amdgcn_mfma_f32_16x16x32_bf16(kfc[t], qfrag, zero4, 0, 0, 0);

        uint32_t pk[8];
        float psum = 0.f;
        #pragma unroll
        for (int t = 0; t < 4; ++t) {
            const float p0 = __expf(sv[t][0]), p1 = __expf(sv[t][1]);
            const float p2 = __expf(sv[t][2]), p3 = __expf(sv[t][3]);
            psum += (p0+p1)+(p2+p3);
            pk[2*t]   = pk2bf(p0, p1);
            pk[2*t+1] = pk2bf(p2, p3);
        }
        psum += __shfl_xor(psum, 16);
        psum += __shfl_xor(psum, 32);
        l += psum;

        #pragma unroll
        for (int t = 0; t < 4; ++t) {
            const int a = q*128 + ((t*32 + g*8) ^ swq);
            uint2 u; u.x = pk[2*t]; u.y = pk[2*t+1];
            *reinterpret_cast<uint2*>(ptw + a) = u;
        }
        // stage LO channels (0..31) into the wave-private slice
        #pragma unroll
        for (int s = 0; s < 4; ++s)
            *reinterpret_cast<u32x4*>(vdst0 + s*1024) = vreg[s];

        loadK(pfmt, kfn);                // prefetch next chunk's K

        __syncthreads();                 // P[buf] visible

        // ---- phase B ----
        // read lo vf first, then overwrite slice with HI channels (in-order per wave)
        bf16x8 vf[8];
        #pragma unroll
        for (int ct = 0; ct < 2; ++ct)
            #pragma unroll
            for (int mm = 0; mm < 2; ++mm)
                vf[ct*2+mm] = *reinterpret_cast<const bf16x8*>(
                    (char*)vt + wv*4096 + (ct*16 + q)*128 + ((mm*64 + g*16) ^ swq));
        #pragma unroll
        for (int s = 0; s < 4; ++s)
            *reinterpret_cast<u32x4*>(vdst0 + s*1024) = vreg[4+s];
        #pragma unroll
        for (int ct = 2; ct < 4; ++ct)
            #pragma unroll
            for (int mm = 0; mm < 2; ++mm)
                vf[ct*2+mm] = *reinterpret_cast<const bf16x8*>(
                    (char*)vt + wv*4096 + ((ct-2)*16 + q)*128 + ((mm*64 + g*16) ^ swq));

        __builtin_amdgcn_s_setprio(1);   // T5: favor MFMA cluster
        #pragma unroll
        for (int mm = 0; mm < 2; ++mm) {
            #pragma unroll
            for (int qt = 0; qt < 4; ++qt) {
                const bf16x8 pb = *reinterpret_cast<const bf16x8*>(
                    (char*)pt[buf] + qt*2048 + q*128 + ((mm*64 + g*16) ^ swq));
                #pragma unroll
                for (int ct = 0; ct < 4; ++ct)
                    acc[ct][qt] = __builtin_amdgcn_mfma_f32_16x16x32_bf16(vf[ct*2+mm], pb, acc[ct][qt], 0, 0, 0);
            }
        }
        __builtin_amdgcn_s_setprio(0);
    };

    bf16x8 kfA[4], kfB[4];
    loadK(mt0, kfA);
    int mt = mt0;
    for (; mt + 1 < mt1; mt += 2) {
        chunk(mt,   kfA, kfB, mt + 1);
        chunk(mt+1, kfB, kfA, (mt + 2 < mt1) ? mt + 2 : mt1 - 1);
    }
    if (mt < mt1) chunk(mt, kfA, kfB, mt);

    if (g == 0)
        lsum[(size_t)((half*4 + b)*N_POS) + qrow] = l;

    if (g == 0) l_s[wv*16 + q] = l;
    __syncthreads();
    float invl[4];
    #pragma unroll
    for (int qt = 0; qt < 4; ++qt) invl[qt] = 1.f / l_s[qt*16 + q];

    char* obase = (char*)o_part + ((size_t)((half*4 + b)*N_POS) + n0)*512;
    #pragma unroll
    for (int qt = 0; qt < 4; ++qt) {
        char* orow = obase + (size_t)(qt*16 + q)*512 + (wv*64 + 4*g)*2;
        #pragma unroll
        for (int ct = 0; ct < 4; ++ct) {
            const uint32_t u0 = pk2bf(acc[ct][qt][0]*invl[qt], acc[ct][qt][1]*invl[qt]);
            const uint32_t u1 = pk2bf(acc[ct][qt][2]*invl[qt], acc[ct][qt][3]*invl[qt]);
            uint2 u; u.x = u0; u.y = u1;
            *reinterpret_cast<uint2*>(orow + ct*32) = u;
        }
    }
}

// ---------------- merge ns splits + transpose + gamma*out + x ----------------
__global__ __launch_bounds__(256) void out_combine(
    const ushort* __restrict__ o_part, const float* __restrict__ lsum,
    const float* __restrict__ x, const float* __restrict__ gamma,
    float* __restrict__ out, int nsplit)
{
    __shared__ float t[64][65];
    __shared__ float w_s[4][64];
    const int tid = threadIdx.x;
    const int nt = blockIdx.x;
    const int ct = blockIdx.y;
    const int b  = blockIdx.z;
    const int n0 = nt*64, c0 = ct*64;
    const float gm = gamma[0];
    const size_t SPLIT = (size_t)4*N_POS*C_DIM;

    if (tid < 64) {
        float e[4];
        float sum = 0.f;
        for (int s = 0; s < nsplit; ++s) {
            e[s] = lsum[(size_t)((s*4 + b)*N_POS) + n0 + tid];
            sum += e[s];
        }
        const float inv = 1.f / sum;
        for (int s = 0; s < nsplit; ++s)
            w_s[s][tid] = e[s] * inv;
    }
    __syncthreads();

    #pragma unroll
    for (int ii = 0; ii < 2; ++ii) {
        const int item = ii*256 + tid;
        const int nl = item >> 3;
        const int oc = item & 7;
        const size_t off = ((size_t)(b*N_POS) + n0 + nl)*C_DIM + c0 + oc*8;
        float a0=0.f,a1=0.f,a2=0.f,a3=0.f,a4=0.f,a5=0.f,a6=0.f,a7=0.f;
        for (int s = 0; s < nsplit; ++s) {
            const uint4 d = *reinterpret_cast<const uint4*>(o_part + s*SPLIT + off);
            const float w = w_s[s][nl];
            a0 += w*bf2f_lo(d.x); a1 += w*bf2f_hi(d.x);
            a2 += w*bf2f_lo(d.y); a3 += w*bf2f_hi(d.y);
            a4 += w*bf2f_lo(d.z); a5 += w*bf2f_hi(d.z);
            a6 += w*bf2f_lo(d.w); a7 += w*bf2f_hi(d.w);
        }
        float* tr = &t[nl][oc*8];
        tr[0]=a0; tr[1]=a1; tr[2]=a2; tr[3]=a3; tr[4]=a4; tr[5]=a5; tr[6]=a6; tr[7]=a7;
    }
    __syncthreads();
    {
        const int jj4 = (tid & 15) * 4;
        const int cg  = tid >> 4;
        #pragma unroll
        for (int ii = 0; ii < 4; ++ii) {
            const int cl = ii*16 + cg;
            const size_t idx = ((size_t)(b*C_DIM) + c0 + cl)*N_POS + n0 + jj4;
            const float4 xv = *reinterpret_cast<const float4*>(&x[idx]);
            float4 o;
            o.x = gm * t[jj4+0][cl] + xv.x;
            o.y = gm * t[jj4+1][cl] + xv.y;
            o.z = gm * t[jj4+2][cl] + xv.z;
            o.w = gm * t[jj4+3][cl] + xv.w;
            *reinterpret_cast<float4*>(&out[idx]) = o;
        }
    }
}

extern "C" void kernel_launch(void* const* d_in, const int* in_sizes, int n_in,
                              void* d_out, int out_size, void* d_ws, size_t ws_size,
                              hipStream_t stream)
{
    const float* x     = (const float*)d_in[0];
    const float* Wq    = (const float*)d_in[1];
    const float* bq    = (const float*)d_in[2];
    const float* Wk    = (const float*)d_in[3];
    const float* bk    = (const float*)d_in[4];
    const float* Wv    = (const float*)d_in[5];
    const float* bv    = (const float*)d_in[6];
    const float* gamma = (const float*)d_in[7];

    // Choose split count from ws capacity (deterministic: ws_size is constant).
    // ns=4 needs: o_part 32MB + lsum 256KB + q 1MB + k 1MB + v 8MB + W 160KB + bias.
    const size_t need4 =
        (size_t)4*4*N_POS*C_DIM*2 + (size_t)4*4*N_POS*4 +
        (size_t)4*N_POS*CQK_D*2*2 + (size_t)4*C_DIM*N_POS*2 + 320*C_DIM*2 + 320*4;
    const int ns = (ws_size >= need4) ? 4 : 3;

    ushort* o_part = (ushort*)d_ws;
    ushort* xT_bf  = (ushort*)d_ws;                       // alias, dead before flash writes
    float*  lsum   = (float*)(o_part + (size_t)ns*4*N_POS*C_DIM);
    ushort* q_bf   = (ushort*)(lsum + (size_t)ns*4*N_POS);
    ushort* k_bf   = q_bf + (size_t)4*N_POS*CQK_D;
    ushort* v_bf   = k_bf + (size_t)4*N_POS*CQK_D;
    ushort* W_bf   = v_bf + (size_t)4*C_DIM*N_POS;
    float*  bias_f = (float*)(W_bf + 320*C_DIM);
    float* out = (float*)d_out;

    prep<<<dim3(65,4,4), 256, 0, stream>>>(x, Wq, bq, Wk, bk, Wv, bv, xT_bf, W_bf, bias_f);
    qkv_gemm<<<dim3(64,4,4), 256, 0, stream>>>(xT_bf, W_bf, bias_f, q_bf, k_bf, v_bf);
    flash_mfma<<<dim3(64,ns,4), 256, 0, stream>>>(q_bf, k_bf, v_bf, o_part, lsum, ns);
    out_combine<<<dim3(64,4,4), 256, 0, stream>>>(o_part, lsum, x, gamma, out, ns);
}

// Round 26
// 95.825 us; speedup vs baseline: 3.0665x; 3.0665x over previous
//
#include <hip/hip_runtime.h>
#include <hip/hip_bf16.h>
#include <math.h>
#include <stdint.h>

#define N_POS 4096
#define C_DIM 256
#define CQK_D 32
#define NSPLIT 3

typedef __attribute__((ext_vector_type(8))) short bf16x8;
typedef __attribute__((ext_vector_type(4))) float f32x4;
typedef __attribute__((ext_vector_type(4))) uint32_t u32x4;

// bf16 conversions via HIP intrinsics: compiler folds pairs to v_cvt_pk_bf16_f32
// (1 op/pair vs 5-op manual RTNE emulation). Same RTNE rounding.
__device__ inline uint16_t f2bf(float f){
  union { __hip_bfloat16 h; uint16_t u; } c;
  c.h = __float2bfloat16(f);
  return c.u;
}
__device__ inline uint32_t pk2bf(float a, float b){
  union { __hip_bfloat162 h; uint32_t u; } c;
  c.h = __float22bfloat162_rn(float2{a, b});
  return c.u;
}
__device__ inline float bf2f_lo(uint32_t d){ return __uint_as_float(d << 16); }
__device__ inline float bf2f_hi(uint32_t d){ return __uint_as_float(d & 0xFFFF0000u); }

// ---------------- prep: x transpose -> xT_bf [B][N][256], W concat -> W_bf[320][256], bias_f[320]
__global__ __launch_bounds__(256) void prep(
    const float* __restrict__ x,
    const float* __restrict__ Wq, const float* __restrict__ bq,
    const float* __restrict__ Wk, const float* __restrict__ bk,
    const float* __restrict__ Wv, const float* __restrict__ bv,
    ushort* __restrict__ xT_bf, ushort* __restrict__ W_bf, float* __restrict__ bias_f)
{
    const int tid = threadIdx.x;
    if (blockIdx.x == 64) {
        // W conversion, vectorized: 16 sub-blocks x 5120 elems; float4 in, uint2(4 bf16) out
        const int sub = blockIdx.z * 4 + blockIdx.y;   // 0..15
        const int e0 = sub * 5120;
        #pragma unroll
        for (int it = 0; it < 5; ++it) {
            const int e = e0 + (it*256 + tid)*4;       // 4-aligned, same row for all 4
            const int o = e >> 8, c = e & 255;
            float4 w;
            if (o < 32)       w = *reinterpret_cast<const float4*>(&Wq[o*C_DIM + c]);
            else if (o < 64)  w = *reinterpret_cast<const float4*>(&Wk[(o-32)*C_DIM + c]);
            else              w = *reinterpret_cast<const float4*>(&Wv[(o-64)*C_DIM + c]);
            uint2 u; u.x = pk2bf(w.x, w.y); u.y = pk2bf(w.z, w.w);
            *reinterpret_cast<uint2*>(W_bf + e) = u;
        }
        if (sub == 0) {
            for (int i = tid; i < 320; i += 256)
                bias_f[i] = (i < 32) ? bq[i] : (i < 64) ? bk[i-32] : bv[i-64];
        }
        return;
    }
    __shared__ float t[64][65];
    const int jj4 = (tid & 15) * 4;     // n within tile (float4)
    const int rg  = tid >> 4;           // 0..15
    const int n0 = blockIdx.x * 64;
    const int c0 = blockIdx.y * 64;
    const int b  = blockIdx.z;
    // phase 1 (vectorized): float4 x reads, 4 iters x 16 rows
    #pragma unroll
    for (int ii = 0; ii < 4; ++ii) {
        const int cl = ii*16 + rg;
        const float4 xv = *reinterpret_cast<const float4*>(
            &x[((size_t)(b*C_DIM) + c0 + cl)*N_POS + n0 + jj4]);
        float* tr = &t[cl][jj4];
        tr[0] = xv.x; tr[1] = xv.y; tr[2] = xv.z; tr[3] = xv.w;
    }
    __syncthreads();
    #pragma unroll
    for (int ii = 0; ii < 8; ++ii) {
        const int flat = ii*256 + tid;
        const int nl = flat >> 5;
        const int cp = flat & 31;
        const uint32_t d = pk2bf(t[2*cp][nl], t[2*cp+1][nl]);
        *reinterpret_cast<uint32_t*>(xT_bf + ((size_t)(b*N_POS) + n0 + nl)*C_DIM + c0 + 2*cp) = d;
    }
}

// ---------------- qkv projection as bf16 MFMA GEMM (o-split x4) ----------------
__global__ __launch_bounds__(256, 4) void qkv_gemm(
    const ushort* __restrict__ xT_bf, const ushort* __restrict__ W_bf,
    const float* __restrict__ bias_f,
    ushort* __restrict__ q_bf, ushort* __restrict__ k_bf, ushort* __restrict__ v_bf)
{
    __shared__ ushort xs[64*C_DIM];      // 32 KB, XOR-swizzled rows of 512B
    const int tid  = threadIdx.x;
    const int wv   = tid >> 6;
    const int lane = tid & 63;
    const int g    = lane >> 4;
    const int q    = lane & 15;
    const int y    = blockIdx.y;         // o-quarter: ot = y*5 .. y*5+4
    const int b    = blockIdx.z;
    const int n0   = blockIdx.x * 64;

    {
        const char* xTb = (const char*)(xT_bf + ((size_t)(b*N_POS) + n0)*C_DIM);
        const int n_l    = (tid*16) >> 9;
        const int inner  = (tid & 31) << 4;
        #pragma unroll
        for (int s = 0; s < 8; ++s) {
            const int n = s*8 + n_l;
            const int src_inner = inner ^ ((n & 7) << 4);
            __builtin_amdgcn_global_load_lds(
                (const __attribute__((address_space(1))) uint32_t*)(xTb + (size_t)n*512 + src_inner),
                (__attribute__((address_space(3))) uint32_t*)((char*)xs + s*4096 + wv*1024),
                16, 0, 0);
        }
    }
    __syncthreads();

    f32x4 zero4 = {0.f,0.f,0.f,0.f};
    f32x4 acc[5];
    #pragma unroll
    for (int i = 0; i < 5; ++i) acc[i] = zero4;

    const char* xrow = (const char*)xs + (wv*16 + q)*512;
    const int sw = (q & 7) << 4;

    #pragma unroll
    for (int kk = 0; kk < 8; ++kk) {
        const bf16x8 xf = *reinterpret_cast<const bf16x8*>(xrow + ((kk*64 + g*16) ^ sw));
        const ushort* wrow = W_bf + (y*80 + q)*C_DIM + kk*32 + g*8;
        #pragma unroll
        for (int i = 0; i < 5; ++i) {
            const bf16x8 wf = *reinterpret_cast<const bf16x8*>(wrow + i*16*C_DIM);
            acc[i] = __builtin_amdgcn_mfma_f32_16x16x32_bf16(wf, xf, acc[i], 0, 0, 0);
        }
    }

    const int n = n0 + wv*16 + q;
    #pragma unroll
    for (int i = 0; i < 5; ++i) {
        const int got = y*5 + i;
        const int ob  = got*16 + 4*g;
        const float4 bi = *reinterpret_cast<const float4*>(bias_f + ob);
        if (got < 4) {
            const uint32_t u0 = pk2bf(acc[i][0] + bi.x, acc[i][1] + bi.y);
            const uint32_t u1 = pk2bf(acc[i][2] + bi.z, acc[i][3] + bi.w);
            ushort* dst = (got < 2 ? q_bf : k_bf) + ((size_t)(b*N_POS) + n)*CQK_D + (ob & 31);
            uint2 u; u.x = u0; u.y = u1;
            *reinterpret_cast<uint2*>(dst) = u;
        } else {
            const int c = ob - 64;
            ushort* vB = v_bf + (size_t)(b*C_DIM)*N_POS + n;
            vB[(size_t)(c+0)*N_POS] = f2bf(acc[i][0] + bi.x);
            vB[(size_t)(c+1)*N_POS] = f2bf(acc[i][1] + bi.y);
            vB[(size_t)(c+2)*N_POS] = f2bf(acc[i][2] + bi.z);
            vB[(size_t)(c+3)*N_POS] = f2bf(acc[i][3] + bi.w);
        }
    }
}

// ---------------- Flash attention: split-KV x3, channel-split PV ----------------
// r12 structure (verified ~60us across many reproductions): 1 barrier/chunk,
// P ping-pong, V wave-private LDS slice, no-max softmax.
__global__ __launch_bounds__(256, 3) void flash_mfma(
    const ushort* __restrict__ q_bf, const ushort* __restrict__ k_bf,
    const ushort* __restrict__ v_bf, ushort* __restrict__ o_part,
    float* __restrict__ lsum)
{
    __shared__ ushort vt[C_DIM*64];      // 32 KB: per-wave 8KB slice [64c][64k] swizzled
    __shared__ ushort pt[2][4*16*64];    // 2 x 8 KB, [buf][qblock][16q][64k] swizzled
    __shared__ float  l_s[64];

    const int tid  = threadIdx.x;
    const int wv   = tid >> 6;
    const int lane = tid & 63;
    const int g    = lane >> 4;
    const int q    = lane & 15;
    const int half = blockIdx.y;         // 0..2
    const int b    = blockIdx.z;
    const int n0   = blockIdx.x * 64;
    const int qrow = n0 + wv*16 + q;
    const int mt0  = (half == 0) ? 0 : 22 + (half-1)*21;
    const int mt1  = mt0 + ((half == 0) ? 22 : 21);

    const ushort* qb = q_bf + (size_t)b*N_POS*CQK_D;
    const ushort* kb = k_bf + (size_t)b*N_POS*CQK_D;
    const ushort* vb = v_bf + (size_t)b*C_DIM*N_POS;

    const bf16x8 qfrag = *reinterpret_cast<const bf16x8*>(qb + (size_t)qrow*CQK_D + g*8);

    f32x4 zero4 = {0.f, 0.f, 0.f, 0.f};
    f32x4 acc[4][4];                     // [ct][qt]
    #pragma unroll
    for (int i = 0; i < 4; ++i)
        #pragma unroll
        for (int j = 0; j < 4; ++j) acc[i][j] = zero4;
    float l = 0.f;

    const int swq = (q & 7) << 4;
    const int st_hi = lane >> 3, st_lo = lane & 7;
    const ushort* vsrc0 = vb + (size_t)(wv*64 + st_hi)*N_POS + st_lo*8;
    char* vdst0 = (char*)vt + (wv*64 + st_hi)*128 + (((st_lo ^ st_hi) & 7) << 4);

    auto loadK = [&](int mtx, bf16x8* kf) {
        const int mm = mtx * 64;
        #pragma unroll
        for (int t = 0; t < 4; ++t)
            kf[t] = *reinterpret_cast<const bf16x8*>(kb + (size_t)(mm + t*16 + q)*CQK_D + g*8);
    };

    auto chunk = [&](int mtx, bf16x8* kfc, bf16x8* kfn, int pfmt) {
        const int m0 = mtx * 64;
        const int buf = mtx & 1;
        char* ptw = (char*)pt[buf] + wv*2048;

        // ---- phase A ----
        u32x4 vreg[8];                   // issue V loads early (T14)
        #pragma unroll
        for (int s = 0; s < 8; ++s)
            vreg[s] = *reinterpret_cast<const u32x4*>(vsrc0 + (size_t)s*8*N_POS + m0);

        f32x4 sv[4];
        #pragma unroll
        for (int t = 0; t < 4; ++t)
            sv[t] = __builtin_amdgcn_mfma_f32_16x16x32_bf16(kfc[t], qfrag, zero4, 0, 0, 0);

        uint32_t pk[8];
        float psum = 0.f;
        #pragma unroll
        for (int t = 0; t < 4; ++t) {
            const float p0 = __expf(sv[t][0]), p1 = __expf(sv[t][1]);
            const float p2 = __expf(sv[t][2]), p3 = __expf(sv[t][3]);
            psum += (p0+p1)+(p2+p3);
            pk[2*t]   = pk2bf(p0, p1);
            pk[2*t+1] = pk2bf(p2, p3);
        }
        psum += __shfl_xor(psum, 16);
        psum += __shfl_xor(psum, 32);
        l += psum;

        // P writes: pairs are contiguous -> ds_write_b64
        #pragma unroll
        for (int t = 0; t < 4; ++t) {
            const int a = q*128 + ((t*32 + g*8) ^ swq);
            uint2 u; u.x = pk[2*t]; u.y = pk[2*t+1];
            *reinterpret_cast<uint2*>(ptw + a) = u;
        }
        // V writes into wave-private slice (no barrier needed for these)
        #pragma unroll
        for (int s = 0; s < 8; ++s)
            *reinterpret_cast<u32x4*>(vdst0 + s*1024) = vreg[s];

        loadK(pfmt, kfn);                // prefetch next chunk's K

        __syncthreads();                 // P[buf] visible

        // ---- phase B ----
        bf16x8 vf[8];
        #pragma unroll
        for (int ct = 0; ct < 4; ++ct)
            #pragma unroll
            for (int mm = 0; mm < 2; ++mm)
                vf[ct*2+mm] = *reinterpret_cast<const bf16x8*>(
                    (char*)vt + (wv*64 + ct*16 + q)*128 + ((mm*64 + g*16) ^ swq));

        __builtin_amdgcn_s_setprio(1);   // T5: favor MFMA cluster
        #pragma unroll
        for (int mm = 0; mm < 2; ++mm) {
            #pragma unroll
            for (int qt = 0; qt < 4; ++qt) {
                const bf16x8 pb = *reinterpret_cast<const bf16x8*>(
                    (char*)pt[buf] + qt*2048 + q*128 + ((mm*64 + g*16) ^ swq));
                #pragma unroll
                for (int ct = 0; ct < 4; ++ct)
                    acc[ct][qt] = __builtin_amdgcn_mfma_f32_16x16x32_bf16(vf[ct*2+mm], pb, acc[ct][qt], 0, 0, 0);
            }
        }
        __builtin_amdgcn_s_setprio(0);
    };

    bf16x8 kfA[4], kfB[4];
    loadK(mt0, kfA);
    int mt = mt0;
    for (; mt + 1 < mt1; mt += 2) {
        chunk(mt,   kfA, kfB, mt + 1);
        chunk(mt+1, kfB, kfA, (mt + 2 < mt1) ? mt + 2 : mt1 - 1);
    }
    if (mt < mt1) chunk(mt, kfA, kfB, mt);

    // write l for merge (wave owns q-block wv)
    if (g == 0)
        lsum[(size_t)((half*4 + b)*N_POS) + qrow] = l;

    // exchange l across waves
    if (g == 0) l_s[wv*16 + q] = l;
    __syncthreads();
    float invl[4];
    #pragma unroll
    for (int qt = 0; qt < 4; ++qt) invl[qt] = 1.f / l_s[qt*16 + q];

    // write o_part: lane (g,q), acc[ct][qt] regs r -> c = wv*64+ct*16+4g+r, n = n0+qt*16+q
    char* obase = (char*)o_part + ((size_t)((half*4 + b)*N_POS) + n0)*512;
    #pragma unroll
    for (int qt = 0; qt < 4; ++qt) {
        char* orow = obase + (size_t)(qt*16 + q)*512 + (wv*64 + 4*g)*2;
        #pragma unroll
        for (int ct = 0; ct < 4; ++ct) {
            const uint32_t u0 = pk2bf(acc[ct][qt][0]*invl[qt], acc[ct][qt][1]*invl[qt]);
            const uint32_t u1 = pk2bf(acc[ct][qt][2]*invl[qt], acc[ct][qt][3]*invl[qt]);
            uint2 u; u.x = u0; u.y = u1;
            *reinterpret_cast<uint2*>(orow + ct*32) = u;
        }
    }
}

// ---------------- merge 3 splits + transpose + gamma*out + x ----------------
__global__ __launch_bounds__(256) void out_combine(
    const ushort* __restrict__ o_part, const float* __restrict__ lsum,
    const float* __restrict__ x, const float* __restrict__ gamma,
    float* __restrict__ out)
{
    __shared__ float t[64][65];
    __shared__ float w0s[64], w1s[64], w2s[64];
    const int tid = threadIdx.x;
    const int nt = blockIdx.x;
    const int ct = blockIdx.y;
    const int b  = blockIdx.z;
    const int n0 = nt*64, c0 = ct*64;
    const float gm = gamma[0];

    if (tid < 64) {
        const float e0 = lsum[(size_t)((0*4 + b)*N_POS) + n0 + tid];
        const float e1 = lsum[(size_t)((1*4 + b)*N_POS) + n0 + tid];
        const float e2 = lsum[(size_t)((2*4 + b)*N_POS) + n0 + tid];
        const float inv = 1.f / (e0 + e1 + e2);
        w0s[tid] = e0 * inv;
        w1s[tid] = e1 * inv;
        w2s[tid] = e2 * inv;
    }
    __syncthreads();

    // phase 1 (vectorized): uint4 = 8 bf16 per o_part read, 2 iters
    #pragma unroll
    for (int ii = 0; ii < 2; ++ii) {
        const int item = ii*256 + tid;       // 0..511
        const int nl = item >> 3;            // 0..63
        const int oc = item & 7;             // c-octet 0..7
        const size_t off = ((size_t)(b*N_POS) + n0 + nl)*C_DIM + c0 + oc*8;
        const uint4 d0 = *reinterpret_cast<const uint4*>(o_part + off);
        const uint4 d1 = *reinterpret_cast<const uint4*>(o_part + (size_t)4*N_POS*C_DIM + off);
        const uint4 d2 = *reinterpret_cast<const uint4*>(o_part + (size_t)8*N_POS*C_DIM + off);
        const float w0 = w0s[nl], w1 = w1s[nl], w2 = w2s[nl];
        float* tr = &t[nl][oc*8];
        tr[0] = w0*bf2f_lo(d0.x) + w1*bf2f_lo(d1.x) + w2*bf2f_lo(d2.x);
        tr[1] = w0*bf2f_hi(d0.x) + w1*bf2f_hi(d1.x) + w2*bf2f_hi(d2.x);
        tr[2] = w0*bf2f_lo(d0.y) + w1*bf2f_lo(d1.y) + w2*bf2f_lo(d2.y);
        tr[3] = w0*bf2f_hi(d0.y) + w1*bf2f_hi(d1.y) + w2*bf2f_hi(d2.y);
        tr[4] = w0*bf2f_lo(d0.z) + w1*bf2f_lo(d1.z) + w2*bf2f_lo(d2.z);
        tr[5] = w0*bf2f_hi(d0.z) + w1*bf2f_hi(d1.z) + w2*bf2f_hi(d2.z);
        tr[6] = w0*bf2f_lo(d0.w) + w1*bf2f_lo(d1.w) + w2*bf2f_lo(d2.w);
        tr[7] = w0*bf2f_hi(d0.w) + w1*bf2f_hi(d1.w) + w2*bf2f_hi(d2.w);
    }
    __syncthreads();
    // phase 2 (vectorized): float4 x-reads + float4 out-writes, 4 iters
    {
        const int jj4 = (tid & 15) * 4;   // n quad
        const int cg  = tid >> 4;         // 0..15
        #pragma unroll
        for (int ii = 0; ii < 4; ++ii) {
            const int cl = ii*16 + cg;
            const size_t idx = ((size_t)(b*C_DIM) + c0 + cl)*N_POS + n0 + jj4;
            const float4 xv = *reinterpret_cast<const float4*>(&x[idx]);
            float4 o;
            o.x = gm * t[jj4+0][cl] + xv.x;
            o.y = gm * t[jj4+1][cl] + xv.y;
            o.z = gm * t[jj4+2][cl] + xv.z;
            o.w = gm * t[jj4+3][cl] + xv.w;
            *reinterpret_cast<float4*>(&out[idx]) = o;
        }
    }
}

extern "C" void kernel_launch(void* const* d_in, const int* in_sizes, int n_in,
                              void* d_out, int out_size, void* d_ws, size_t ws_size,
                              hipStream_t stream)
{
    const float* x     = (const float*)d_in[0];
    const float* Wq    = (const float*)d_in[1];
    const float* bq    = (const float*)d_in[2];
    const float* Wk    = (const float*)d_in[3];
    const float* bk    = (const float*)d_in[4];
    const float* Wv    = (const float*)d_in[5];
    const float* bv    = (const float*)d_in[6];
    const float* gamma = (const float*)d_in[7];

    // ws layout (aliased): [0,24MB) = o_part (flash+) OVERLAPS xT_bf [0,8MB) (prep->qkv only)
    // then: lsum 192KB | q_bf 1MB | k_bf 1MB | v_bf 8MB | W_bf 160KB | bias ~ total <35MB
    ushort* o_part = (ushort*)d_ws;
    ushort* xT_bf  = (ushort*)d_ws;                       // alias, dead before flash writes
    float*  lsum   = (float*)(o_part + (size_t)NSPLIT*4*N_POS*C_DIM);
    ushort* q_bf   = (ushort*)(lsum + (size_t)NSPLIT*4*N_POS);
    ushort* k_bf   = q_bf + (size_t)4*N_POS*CQK_D;
    ushort* v_bf   = k_bf + (size_t)4*N_POS*CQK_D;
    ushort* W_bf   = v_bf + (size_t)4*C_DIM*N_POS;
    float*  bias_f = (float*)(W_bf + 320*C_DIM);
    float* out = (float*)d_out;

    prep<<<dim3(65,4,4), 256, 0, stream>>>(x, Wq, bq, Wk, bk, Wv, bv, xT_bf, W_bf, bias_f);
    qkv_gemm<<<dim3(64,4,4), 256, 0, stream>>>(xT_bf, W_bf, bias_f, q_bf, k_bf, v_bf);
    flash_mfma<<<dim3(64,NSPLIT,4), 256, 0, stream>>>(q_bf, k_bf, v_bf, o_part, lsum);
    out_combine<<<dim3(64,4,4), 256, 0, stream>>>(o_part, lsum, x, gamma, out);
}